// Round 15
// baseline (192.977 us; speedup 1.0000x reference)
//
#include <hip/hip_runtime.h>
#include <stdint.h>
#include <stddef.h>

// ---------- types ----------
typedef __attribute__((ext_vector_type(8))) short s16x8;
typedef __attribute__((ext_vector_type(4))) short s16x4;
typedef __attribute__((ext_vector_type(4))) float f32x4;
typedef __attribute__((ext_vector_type(2))) unsigned int u32x2;

#define S_LEN 2048
#define HID 2048
#define QKV_N 3072
#define NHEAD 32
#define NKVH 8

__device__ __forceinline__ unsigned short f2bf(float f) {
  union { float f; unsigned u; } a; a.f = f;
  unsigned u = a.u;
  u += 0x7fffu + ((u >> 16) & 1u);
  return (unsigned short)(u >> 16);
}
__device__ __forceinline__ unsigned cvt_pk_bf16(float a, float b) {
  unsigned r;
  asm("v_cvt_pk_bf16_f32 %0, %1, %2" : "=v"(r) : "v"(a), "v"(b));
  return r;  // low16 = bf16(a), high16 = bf16(b)
}
__device__ __forceinline__ void gl_lds16(const unsigned short* g, short* l) {
  __builtin_amdgcn_global_load_lds(
      (const __attribute__((address_space(1))) unsigned int*)g,
      (__attribute__((address_space(3))) unsigned int*)l, 16, 0, 0);
}

// ---------- 1) fp32 -> bf16 convert ----------
__global__ void k_convert(const float* __restrict__ x, const float* __restrict__ wq,
                          const float* __restrict__ wk, const float* __restrict__ wv,
                          const float* __restrict__ wo, unsigned short* __restrict__ dst) {
  const unsigned n4 = 18874368u / 4u;
  for (unsigned i = blockIdx.x * blockDim.x + threadIdx.x; i < n4;
       i += gridDim.x * blockDim.x) {
    unsigned e = i * 4u;
    const float* src; unsigned off;
    if (e < 8388608u)       { src = x;  off = e; }
    else if (e < 12582912u) { src = wq; off = e - 8388608u; }
    else if (e < 13631488u) { src = wk; off = e - 12582912u; }
    else if (e < 14680064u) { src = wv; off = e - 13631488u; }
    else                    { src = wo; off = e - 14680064u; }
    f32x4 v = *(const f32x4*)(src + off);
    s16x4 o;
    o[0] = (short)f2bf(v[0]); o[1] = (short)f2bf(v[1]);
    o[2] = (short)f2bf(v[2]); o[3] = (short)f2bf(v[3]);
    *(s16x4*)(dst + e) = o;
  }
}

// ---------- 2) RoPE cos/sin table [2048][32] ----------
__global__ void k_rope_table(float* __restrict__ cost, float* __restrict__ sint) {
  int idx = blockIdx.x * 256 + threadIdx.x;
  int i = idx & 31, s = idx >> 5;
  float inv = powf(10000.0f, -(float)(2 * i) / 64.0f);
  float ang = (float)s * inv;
  cost[idx] = cosf(ang);
  sint[idx] = sinf(ang);
}

// ---------- 3) QKV GEMM: 128x128, T4 counted-vmcnt 3-buffer pipeline ----------
// (+bias, +RoPE, Q pre-scale). vmcnt(4) steady, vmcnt(0) final iter. XCD swizzle.
__global__ __launch_bounds__(256) void k_gemm0(
    const unsigned short* __restrict__ A,
    const unsigned short* __restrict__ W0, const unsigned short* __restrict__ W1,
    const unsigned short* __restrict__ W2,
    const float* __restrict__ b0, const float* __restrict__ b1, const float* __restrict__ b2,
    const float* __restrict__ ct, const float* __restrict__ st,
    unsigned short* __restrict__ Cb) {
  __shared__ short lA[3][4096];
  __shared__ short lB[3][4096];
  const int K = 2048;
  int tid = threadIdx.x;
  int wave = tid >> 6, lane = tid & 63;
  int l15 = lane & 15, lg = lane >> 4;
  int nwg = gridDim.x * gridDim.y;
  int f = blockIdx.y * gridDim.x + blockIdx.x;
  f = (f & 7) * (nwg >> 3) + (f >> 3);
  int tn = f % gridDim.x, tm = f / gridDim.x;

  const unsigned short* W; const float* bias; int col0;
  if (tn < 16)      { W = W0; bias = b0; col0 = tn * 128; }
  else if (tn < 20) { W = W1; bias = b1; col0 = (tn - 16) * 128; }
  else              { W = W2; bias = b2; col0 = (tn - 20) * 128; }
  int m0 = tm * 128;
  int wm = wave >> 1, wn = wave & 1;

  const unsigned short* gA0 = A + (size_t)(m0 + (tid >> 2)) * K + (tid & 3) * 8;
  const unsigned short* gA1 = gA0 + (size_t)64 * K;
  const unsigned short* gB0 = W + (size_t)(col0 + (tid >> 2)) * K + (tid & 3) * 8;
  const unsigned short* gB1 = gB0 + (size_t)64 * K;

  f32x4 acc[4][4];
#pragma unroll
  for (int m = 0; m < 4; ++m)
#pragma unroll
    for (int n = 0; n < 4; ++n) acc[m][n] = (f32x4){0.f, 0.f, 0.f, 0.f};

#pragma unroll
  for (int p = 0; p < 2; ++p) {
    int off = p * 32;
    gl_lds16(gA0 + off, &lA[p][wave * 512]);
    gl_lds16(gA1 + off, &lA[p][2048 + wave * 512]);
    gl_lds16(gB0 + off, &lB[p][wave * 512]);
    gl_lds16(gB1 + off, &lB[p][2048 + wave * 512]);
  }

  int cur = 0;
  for (int kt = 0; kt < 64; ++kt) {
    if (kt < 63) asm volatile("s_waitcnt vmcnt(4)" ::: "memory");
    else         asm volatile("s_waitcnt vmcnt(0)" ::: "memory");
    __builtin_amdgcn_s_barrier();
    __builtin_amdgcn_sched_barrier(0);
    if (kt + 2 < 64) {
      int nx = cur + 2; if (nx >= 3) nx -= 3;
      int off = (kt + 2) * 32;
      gl_lds16(gA0 + off, &lA[nx][wave * 512]);
      gl_lds16(gA1 + off, &lA[nx][2048 + wave * 512]);
      gl_lds16(gB0 + off, &lB[nx][wave * 512]);
      gl_lds16(gB1 + off, &lB[nx][2048 + wave * 512]);
    }
    s16x8 af[4], bfr[4];
    const short* pa = &lA[cur][(wm * 64 + l15) * 32 + lg * 8];
    const short* pb = &lB[cur][(wn * 64 + l15) * 32 + lg * 8];
#pragma unroll
    for (int m = 0; m < 4; ++m) af[m] = *(const s16x8*)(pa + m * 512);
#pragma unroll
    for (int n = 0; n < 4; ++n) bfr[n] = *(const s16x8*)(pb + n * 512);
    __builtin_amdgcn_s_setprio(1);
#pragma unroll
    for (int m = 0; m < 4; ++m)
#pragma unroll
      for (int n = 0; n < 4; ++n)
        acc[m][n] = __builtin_amdgcn_mfma_f32_16x16x32_bf16(af[m], bfr[n], acc[m][n], 0, 0, 0);
    __builtin_amdgcn_s_setprio(0);
    cur = (cur + 1 == 3) ? 0 : cur + 1;
  }

  const float CSC = 0.125f * 1.44269504f;  // attn scale * log2(e), folded into Q
  bool rope = (tn < 20);
  bool isq = (tn < 16);
#pragma unroll
  for (int n = 0; n < 2; ++n) {
    int lcol = col0 + wn * 64 + n * 16 + l15;
    int gcol = tn * 128 + wn * 64 + n * 16 + l15;
    float blo = bias[lcol], bhi = bias[lcol + 32];
    int i = n * 16 + l15;
#pragma unroll
    for (int m = 0; m < 4; ++m) {
      int row = m0 + wm * 64 + m * 16 + lg * 4;
#pragma unroll
      for (int r = 0; r < 4; ++r) {
        float xl = acc[m][n][r] + blo;
        float xh = acc[m][n + 2][r] + bhi;
        if (rope) {
          int s = (row + r) & (S_LEN - 1);
          float c = ct[s * 32 + i], sn = st[s * 32 + i];
          float nl = xl * c - xh * sn;
          xh = xh * c + xl * sn;
          xl = nl;
          if (isq) { xl *= CSC; xh *= CSC; }
        }
        Cb[(size_t)(row + r) * QKV_N + gcol] = f2bf(xl);
        Cb[(size_t)(row + r) * QKV_N + gcol + 32] = f2bf(xh);
      }
    }
  }
}

// ---------- 6) O-proj GEMM: 128x64 tile, 1024 blocks = 4/CU, T4 pipeline ----------
// Same T4 structure, smaller tile for occupancy (gemm1 was 2 blocks/CU at 128x128).
// 3 loads/tile (A0,A1,B) -> vmcnt(3) steady, vmcnt(0) final. LDS 36KB.
__global__ __launch_bounds__(256, 4) void k_gemm1(
    const unsigned short* __restrict__ A,   // AO bf16 [4096][2048]
    const unsigned short* __restrict__ W,   // Wob bf16 [2048][2048]
    float* __restrict__ Cf) {               // [4096][2048] fp32
  __shared__ short lA[3][4096];  // 128 x 32
  __shared__ short lB[3][2048];  // 64 x 32
  const int K = 2048;
  int tid = threadIdx.x;
  int wave = tid >> 6, lane = tid & 63;
  int l15 = lane & 15, lg = lane >> 4;
  int nwg = 1024;
  int f = blockIdx.x;
  f = (f & 7) * (nwg >> 3) + (f >> 3);   // bijective XCD swizzle
  int tn = f & 31, tm = f >> 5;
  int m0 = tm * 128, col0 = tn * 64;
  int wm = wave >> 1, wn = wave & 1;     // wave -> 64x32 output subtile

  const unsigned short* gA0 = A + (size_t)(m0 + (tid >> 2)) * K + (tid & 3) * 8;
  const unsigned short* gA1 = gA0 + (size_t)64 * K;
  const unsigned short* gB0 = W + (size_t)(col0 + (tid >> 2)) * K + (tid & 3) * 8;

  f32x4 acc[4][2];
#pragma unroll
  for (int m = 0; m < 4; ++m)
#pragma unroll
    for (int n = 0; n < 2; ++n) acc[m][n] = (f32x4){0.f, 0.f, 0.f, 0.f};

  // prologue: stage tiles 0,1 (3 loads each -> 6 in flight)
#pragma unroll
  for (int p = 0; p < 2; ++p) {
    int off = p * 32;
    gl_lds16(gA0 + off, &lA[p][wave * 512]);
    gl_lds16(gA1 + off, &lA[p][2048 + wave * 512]);
    gl_lds16(gB0 + off, &lB[p][wave * 512]);
  }

  int cur = 0;
  for (int kt = 0; kt < 64; ++kt) {
    if (kt < 63) asm volatile("s_waitcnt vmcnt(3)" ::: "memory");
    else         asm volatile("s_waitcnt vmcnt(0)" ::: "memory");
    __builtin_amdgcn_s_barrier();
    __builtin_amdgcn_sched_barrier(0);
    if (kt + 2 < 64) {
      int nx = cur + 2; if (nx >= 3) nx -= 3;
      int off = (kt + 2) * 32;
      gl_lds16(gA0 + off, &lA[nx][wave * 512]);
      gl_lds16(gA1 + off, &lA[nx][2048 + wave * 512]);
      gl_lds16(gB0 + off, &lB[nx][wave * 512]);
    }
    s16x8 af[4], bfr[2];
    const short* pa = &lA[cur][(wm * 64 + l15) * 32 + lg * 8];
    const short* pb = &lB[cur][(wn * 32 + l15) * 32 + lg * 8];
#pragma unroll
    for (int m = 0; m < 4; ++m) af[m] = *(const s16x8*)(pa + m * 512);
#pragma unroll
    for (int n = 0; n < 2; ++n) bfr[n] = *(const s16x8*)(pb + n * 512);
    __builtin_amdgcn_s_setprio(1);
#pragma unroll
    for (int m = 0; m < 4; ++m)
#pragma unroll
      for (int n = 0; n < 2; ++n)
        acc[m][n] = __builtin_amdgcn_mfma_f32_16x16x32_bf16(af[m], bfr[n], acc[m][n], 0, 0, 0);
    __builtin_amdgcn_s_setprio(0);
    cur = (cur + 1 == 3) ? 0 : cur + 1;
  }

#pragma unroll
  for (int n = 0; n < 2; ++n) {
    int gcol = col0 + wn * 32 + n * 16 + l15;
#pragma unroll
    for (int m = 0; m < 4; ++m) {
      int row = m0 + wm * 64 + m * 16 + lg * 4;
#pragma unroll
      for (int r = 0; r < 4; ++r)
        Cf[(size_t)(row + r) * HID + gcol] = acc[m][n][r];
    }
  }
}

// ---------- 4) V transpose: V[b*S+s][kv*64+d] -> Vt[((b*8+kv)*64+d)*2048 + s] ----------
__global__ void k_vtrans(const unsigned short* __restrict__ qkv, unsigned short* __restrict__ vt) {
  __shared__ unsigned short t[64][80];
  int ts = blockIdx.x & 63, td = blockIdx.x >> 6;
  int tid = threadIdx.x;
#pragma unroll
  for (int L = 0; L < 2; ++L) {
    int c = L * 256 + tid;
    int row = c >> 3, ch = c & 7;
    const unsigned short* src = qkv + (size_t)(ts * 64 + row) * QKV_N + 2560 + td * 64 + ch * 8;
    s16x8 v = *(const s16x8*)src;
    int cs = (ch * 8) ^ ((row >> 3) << 3);
    *(s16x8*)&t[row][cs] = v;
  }
  __syncthreads();
  int b = (ts * 64) >> 11;
  int s0 = (ts * 64) & (S_LEN - 1);
#pragma unroll
  for (int L = 0; L < 2; ++L) {
    int c = L * 256 + tid;
    int d = c >> 3, sc = c & 7;
    s16x8 o;
#pragma unroll
    for (int j = 0; j < 8; ++j) o[j] = (short)t[sc * 8 + j][d ^ (sc << 3)];
    unsigned short* dst = vt + ((size_t)((b * 8 + td) * 64 + d)) * 2048 + s0 + sc * 8;
    *(s16x8*)dst = o;
  }
}

// ---------- 5) GQA causal flash attention ----------
// block = one 32-row q-tile of one KV group: 8 waves = 4 heads x 2 row-halves.
// No max-tracking (scores bounded; softmax shift-invariant); Q pre-scaled to log2 domain.
__global__ __launch_bounds__(512, 4) void k_attn(const unsigned short* __restrict__ qkv,
                                                 const unsigned short* __restrict__ vt,
                                                 unsigned short* __restrict__ aout) {
  __shared__ unsigned short lK[2][4096];
  __shared__ unsigned short lV[2][4096];
  __shared__ unsigned short pl[8][1024];   // per-wave P tile [16][64], XOR-swizzled
  int wave = threadIdx.x >> 6, lane = threadIdx.x & 63;
  int l15 = lane & 15, lg = lane >> 4;
  int bi = blockIdx.x;            // 0..1023
  int t  = 63 - (bi >> 4);        // longest-first
  int b  = (bi >> 3) & 1;
  int hg = bi & 7;
  int wh = wave >> 1;             // head within KV group (0..3)
  int mh = wave & 1;              // 16-row half
  int h  = hg * 4 + wh;
  int q0 = t * 32 + mh * 16;
  int kbmax = t >> 1;             // block-uniform

  const unsigned short* qb_ = qkv + (size_t)(b * S_LEN) * QKV_N + h * 64;
  const unsigned short* kbase = qkv + (size_t)(b * S_LEN) * QKV_N + 2048 + hg * 64;
  const unsigned short* vbase = vt + (size_t)((b * NKVH + hg) * 64) * 2048;
  unsigned short* pw = &pl[wave][0];
  int sw = (l15 & 7) << 3;        // element-XOR swizzle for this lane's rows

  int srow = wave * 8 + (lane >> 3);
  int ssw = 8 * ((lane & 7) ^ ((lane >> 3) & 7));
  const unsigned short* gk0 = kbase + (size_t)srow * QKV_N + ssw;
  const unsigned short* gv0 = vbase + (size_t)srow * 2048 + ssw;
  short* lkd0 = (short*)&lK[0][wave * 512]; short* lkd1 = (short*)&lK[1][wave * 512];
  short* lvd0 = (short*)&lV[0][wave * 512]; short* lvd1 = (short*)&lV[1][wave * 512];

  // Q fragments (B-operand of swapped QK^T); already scaled by 0.125*log2e
  s16x8 aq[2];
#pragma unroll
  for (int ks = 0; ks < 2; ++ks)
    aq[ks] = *(const s16x8*)(qb_ + (size_t)(q0 + l15) * QKV_N + ks * 32 + lg * 8);

  f32x4 acc[4];
#pragma unroll
  for (int dt = 0; dt < 4; ++dt) acc[dt] = (f32x4){0.f, 0.f, 0.f, 0.f};
  float lrow = 0.f;

  gl_lds16(gk0, lkd0);
  gl_lds16(gv0, lvd0);
  asm volatile("s_waitcnt vmcnt(0)" ::: "memory");
  __syncthreads();

  for (int kb = 0; kb <= kbmax; ++kb) {
    const unsigned short* lk = &lK[kb & 1][0];
    const unsigned short* lv = &lV[kb & 1][0];
    if (kb < kbmax) {
      size_t go = (size_t)(kb + 1) * 64;
      if ((kb & 1) == 0) { gl_lds16(gk0 + go * QKV_N, lkd1); gl_lds16(gv0 + go, lvd1); }
      else               { gl_lds16(gk0 + go * QKV_N, lkd0); gl_lds16(gv0 + go, lvd0); }
    }
    bool need_mask = (kb == kbmax);
    // QK^T (swapped): lane column = q (l15), rows = k
    f32x4 z[4];
    __builtin_amdgcn_s_setprio(1);
#pragma unroll
    for (int nt = 0; nt < 4; ++nt) {
      s16x8 k0 = *(const s16x8*)(lk + (nt * 16 + l15) * 64 + ((lg * 8) ^ sw));
      s16x8 k1 = *(const s16x8*)(lk + (nt * 16 + l15) * 64 + ((32 + lg * 8) ^ sw));
      f32x4 zz = (f32x4){0.f, 0.f, 0.f, 0.f};
      zz = __builtin_amdgcn_mfma_f32_16x16x32_bf16(k0, aq[0], zz, 0, 0, 0);
      zz = __builtin_amdgcn_mfma_f32_16x16x32_bf16(k1, aq[1], zz, 0, 0, 0);
      z[nt] = zz;
    }
    __builtin_amdgcn_s_setprio(0);
    // softmax without max-tracking: P = exp2(s)
    int q = q0 + l15;
    float rs = 0.f;
#pragma unroll
    for (int nt = 0; nt < 4; ++nt) {
      float p[4];
#pragma unroll
      for (int r = 0; r < 4; ++r) {
        float v = z[nt][r];
        if (need_mask) {
          int k = kb * 64 + nt * 16 + lg * 4 + r;
          if (k > q) v = -1.0e30f;
        }
        p[r] = __builtin_amdgcn_exp2f(v);
      }
      rs += (p[0] + p[1]) + (p[2] + p[3]);
      u32x2 w;
      w[0] = cvt_pk_bf16(p[0], p[1]);
      w[1] = cvt_pk_bf16(p[2], p[3]);
      *(u32x2*)(pw + l15 * 64 + ((nt * 16 + lg * 4) ^ sw)) = w;
    }
    rs += __shfl_xor(rs, 16);
    rs += __shfl_xor(rs, 32);
    lrow += rs;
    // P fragments (DS ops wave-ordered: reads see this wave's writes)
    s16x8 pa0 = *(const s16x8*)(pw + l15 * 64 + ((lg * 8) ^ sw));
    s16x8 pa1 = *(const s16x8*)(pw + l15 * 64 + ((32 + lg * 8) ^ sw));
    // PV
    __builtin_amdgcn_s_setprio(1);
#pragma unroll
    for (int dt = 0; dt < 4; ++dt) {
      s16x8 v0 = *(const s16x8*)(lv + (dt * 16 + l15) * 64 + ((lg * 8) ^ sw));
      s16x8 v1 = *(const s16x8*)(lv + (dt * 16 + l15) * 64 + ((32 + lg * 8) ^ sw));
      acc[dt] = __builtin_amdgcn_mfma_f32_16x16x32_bf16(pa0, v0, acc[dt], 0, 0, 0);
      acc[dt] = __builtin_amdgcn_mfma_f32_16x16x32_bf16(pa1, v1, acc[dt], 0, 0, 0);
    }
    __builtin_amdgcn_s_setprio(0);
    asm volatile("s_waitcnt vmcnt(0)" ::: "memory");
    __syncthreads();
  }

  // epilogue: O = acc / l
  unsigned short* ob = aout + (size_t)(b * S_LEN) * HID + h * 64;
#pragma unroll
  for (int r = 0; r < 4; ++r) {
    float lr = __shfl(lrow, lg * 4 + r);
    float inv = 1.0f / lr;
#pragma unroll
    for (int dt = 0; dt < 4; ++dt)
      ob[(size_t)(q0 + lg * 4 + r) * HID + dt * 16 + l15] = f2bf(acc[dt][r] * inv);
  }
}

// ---------- launch ----------
extern "C" void kernel_launch(void* const* d_in, const int* in_sizes, int n_in,
                              void* d_out, int out_size, void* d_ws, size_t ws_size,
                              hipStream_t stream) {
  const float* x  = (const float*)d_in[0];
  const float* qw = (const float*)d_in[1];
  const float* qb = (const float*)d_in[2];
  const float* kw = (const float*)d_in[3];
  const float* kbias = (const float*)d_in[4];
  const float* vw = (const float*)d_in[5];
  const float* vbias = (const float*)d_in[6];
  const float* ow = (const float*)d_in[7];

  unsigned short* Xb  = (unsigned short*)d_ws;          // 8388608
  unsigned short* Wqb = Xb + 8388608;                   // 4194304
  unsigned short* Wkb = Wqb + 4194304;                  // 1048576
  unsigned short* Wvb = Wkb + 1048576;                  // 1048576
  unsigned short* Wob = Wvb + 1048576;                  // 4194304
  unsigned short* QKV = Wob + 4194304;                  // 4096*3072
  unsigned short* VT  = QKV + 12582912;                 // 2*8*64*2048
  unsigned short* AO  = VT + 2097152;                   // 4096*2048
  float* COS = (float*)(AO + 8388608);                  // 65536 f32
  float* SIN = COS + 65536;

  k_convert<<<1024, 256, 0, stream>>>(x, qw, kw, vw, ow, Xb);
  k_rope_table<<<256, 256, 0, stream>>>(COS, SIN);
  k_gemm0<<<dim3(24, 32), 256, 0, stream>>>(Xb, Wqb, Wkb, Wvb, qb, kbias, vbias,
                                            COS, SIN, QKV);
  k_vtrans<<<512, 256, 0, stream>>>(QKV, VT);
  k_attn<<<1024, 512, 0, stream>>>(QKV, VT, AO);
  k_gemm1<<<1024, 256, 0, stream>>>(AO, Wob, (float*)d_out);
}

// Round 16
// 186.876 us; speedup vs baseline: 1.0326x; 1.0326x over previous
//
#include <hip/hip_runtime.h>
#include <stdint.h>
#include <stddef.h>

// ---------- types ----------
typedef __attribute__((ext_vector_type(8))) short s16x8;
typedef __attribute__((ext_vector_type(4))) short s16x4;
typedef __attribute__((ext_vector_type(4))) float f32x4;
typedef __attribute__((ext_vector_type(2))) unsigned int u32x2;

#define S_LEN 2048
#define HID 2048
#define QKV_N 3072
#define NHEAD 32
#define NKVH 8

__device__ __forceinline__ unsigned short f2bf(float f) {
  union { float f; unsigned u; } a; a.f = f;
  unsigned u = a.u;
  u += 0x7fffu + ((u >> 16) & 1u);
  return (unsigned short)(u >> 16);
}
__device__ __forceinline__ unsigned cvt_pk_bf16(float a, float b) {
  unsigned r;
  asm("v_cvt_pk_bf16_f32 %0, %1, %2" : "=v"(r) : "v"(a), "v"(b));
  return r;  // low16 = bf16(a), high16 = bf16(b)
}
__device__ __forceinline__ void gl_lds16(const unsigned short* g, short* l) {
  __builtin_amdgcn_global_load_lds(
      (const __attribute__((address_space(1))) unsigned int*)g,
      (__attribute__((address_space(3))) unsigned int*)l, 16, 0, 0);
}

// ---------- 1) fp32 -> bf16 convert ----------
__global__ void k_convert(const float* __restrict__ x, const float* __restrict__ wq,
                          const float* __restrict__ wk, const float* __restrict__ wv,
                          const float* __restrict__ wo, unsigned short* __restrict__ dst) {
  const unsigned n4 = 18874368u / 4u;
  for (unsigned i = blockIdx.x * blockDim.x + threadIdx.x; i < n4;
       i += gridDim.x * blockDim.x) {
    unsigned e = i * 4u;
    const float* src; unsigned off;
    if (e < 8388608u)       { src = x;  off = e; }
    else if (e < 12582912u) { src = wq; off = e - 8388608u; }
    else if (e < 13631488u) { src = wk; off = e - 12582912u; }
    else if (e < 14680064u) { src = wv; off = e - 13631488u; }
    else                    { src = wo; off = e - 14680064u; }
    f32x4 v = *(const f32x4*)(src + off);
    s16x4 o;
    o[0] = (short)f2bf(v[0]); o[1] = (short)f2bf(v[1]);
    o[2] = (short)f2bf(v[2]); o[3] = (short)f2bf(v[3]);
    *(s16x4*)(dst + e) = o;
  }
}

// ---------- 2) RoPE cos/sin table [2048][32] ----------
__global__ void k_rope_table(float* __restrict__ cost, float* __restrict__ sint) {
  int idx = blockIdx.x * 256 + threadIdx.x;
  int i = idx & 31, s = idx >> 5;
  float inv = powf(10000.0f, -(float)(2 * i) / 64.0f);
  float ang = (float)s * inv;
  cost[idx] = cosf(ang);
  sint[idx] = sinf(ang);
}

// ---------- 3/6) GEMM: C[M,*] = A[M,2048]*W^T (+bias; MODE0: +RoPE, Q pre-scale) ----------
// T4 counted-vmcnt pipeline: 3 LDS buffers, 2 K-tiles in flight, raw s_barrier,
// s_waitcnt vmcnt(4) (never 0 in the main loop; vmcnt(0) on the final iteration to
// close the kt=63 staging race). + bijective XCD swizzle (T1).
template <int MODE>
__global__ __launch_bounds__(256) void k_gemm(
    const unsigned short* __restrict__ A,
    const unsigned short* __restrict__ W0, const unsigned short* __restrict__ W1,
    const unsigned short* __restrict__ W2,
    const float* __restrict__ b0, const float* __restrict__ b1, const float* __restrict__ b2,
    const float* __restrict__ ct, const float* __restrict__ st,
    unsigned short* __restrict__ Cb, float* __restrict__ Cf) {
  __shared__ short lA[3][4096];
  __shared__ short lB[3][4096];
  const int K = 2048;
  int tid = threadIdx.x;
  int wave = tid >> 6, lane = tid & 63;
  int l15 = lane & 15, lg = lane >> 4;
  // XCD swizzle on flattened block id
  int nwg = gridDim.x * gridDim.y;
  int f = blockIdx.y * gridDim.x + blockIdx.x;
  f = (f & 7) * (nwg >> 3) + (f >> 3);
  int tn = f % gridDim.x, tm = f / gridDim.x;

  const unsigned short* W; const float* bias = nullptr; int col0;
  if constexpr (MODE == 0) {
    if (tn < 16)      { W = W0; bias = b0; col0 = tn * 128; }
    else if (tn < 20) { W = W1; bias = b1; col0 = (tn - 16) * 128; }
    else              { W = W2; bias = b2; col0 = (tn - 20) * 128; }
  } else { W = W0; col0 = tn * 128; }
  int m0 = tm * 128;
  int wm = wave >> 1, wn = wave & 1;

  const unsigned short* gA0 = A + (size_t)(m0 + (tid >> 2)) * K + (tid & 3) * 8;
  const unsigned short* gA1 = gA0 + (size_t)64 * K;
  const unsigned short* gB0 = W + (size_t)(col0 + (tid >> 2)) * K + (tid & 3) * 8;
  const unsigned short* gB1 = gB0 + (size_t)64 * K;

  f32x4 acc[4][4];
#pragma unroll
  for (int m = 0; m < 4; ++m)
#pragma unroll
    for (int n = 0; n < 4; ++n) acc[m][n] = (f32x4){0.f, 0.f, 0.f, 0.f};

  // prologue: stage tiles 0 and 1 (8 loads in flight)
#pragma unroll
  for (int p = 0; p < 2; ++p) {
    int off = p * 32;
    gl_lds16(gA0 + off, &lA[p][wave * 512]);
    gl_lds16(gA1 + off, &lA[p][2048 + wave * 512]);
    gl_lds16(gB0 + off, &lB[p][wave * 512]);
    gl_lds16(gB1 + off, &lB[p][2048 + wave * 512]);
  }

  int cur = 0;
  for (int kt = 0; kt < 64; ++kt) {
    // wait for tile kt's 4 loads (issued 2 iters ago); kt+1's 4 stay in flight
    if (kt < 63) asm volatile("s_waitcnt vmcnt(4)" ::: "memory");
    else         asm volatile("s_waitcnt vmcnt(0)" ::: "memory");
    __builtin_amdgcn_s_barrier();
    __builtin_amdgcn_sched_barrier(0);
    if (kt + 2 < 64) {
      int nx = cur + 2; if (nx >= 3) nx -= 3;
      int off = (kt + 2) * 32;
      gl_lds16(gA0 + off, &lA[nx][wave * 512]);
      gl_lds16(gA1 + off, &lA[nx][2048 + wave * 512]);
      gl_lds16(gB0 + off, &lB[nx][wave * 512]);
      gl_lds16(gB1 + off, &lB[nx][2048 + wave * 512]);
    }
    s16x8 af[4], bfr[4];
    const short* pa = &lA[cur][(wm * 64 + l15) * 32 + lg * 8];
    const short* pb = &lB[cur][(wn * 64 + l15) * 32 + lg * 8];
#pragma unroll
    for (int m = 0; m < 4; ++m) af[m] = *(const s16x8*)(pa + m * 512);
#pragma unroll
    for (int n = 0; n < 4; ++n) bfr[n] = *(const s16x8*)(pb + n * 512);
    __builtin_amdgcn_s_setprio(1);
#pragma unroll
    for (int m = 0; m < 4; ++m)
#pragma unroll
      for (int n = 0; n < 4; ++n)
        acc[m][n] = __builtin_amdgcn_mfma_f32_16x16x32_bf16(af[m], bfr[n], acc[m][n], 0, 0, 0);
    __builtin_amdgcn_s_setprio(0);
    cur = (cur + 1 == 3) ? 0 : cur + 1;
  }

  if constexpr (MODE == 0) {
    const float CSC = 0.125f * 1.44269504f;  // attn scale * log2(e), folded into Q
    // epilogue: bias + RoPE for Q/K heads (tn<20), Q also pre-scaled; V passes through.
    bool rope = (tn < 20);
    bool isq = (tn < 16);
#pragma unroll
    for (int n = 0; n < 2; ++n) {
      int lcol = col0 + wn * 64 + n * 16 + l15;
      int gcol = tn * 128 + wn * 64 + n * 16 + l15;
      float blo = bias[lcol], bhi = bias[lcol + 32];
      int i = n * 16 + l15;
#pragma unroll
      for (int m = 0; m < 4; ++m) {
        int row = m0 + wm * 64 + m * 16 + lg * 4;
#pragma unroll
        for (int r = 0; r < 4; ++r) {
          float xl = acc[m][n][r] + blo;
          float xh = acc[m][n + 2][r] + bhi;
          if (rope) {
            int s = (row + r) & (S_LEN - 1);
            float c = ct[s * 32 + i], sn = st[s * 32 + i];
            float nl = xl * c - xh * sn;
            xh = xh * c + xl * sn;
            xl = nl;
            if (isq) { xl *= CSC; xh *= CSC; }
          }
          Cb[(size_t)(row + r) * QKV_N + gcol] = f2bf(xl);
          Cb[(size_t)(row + r) * QKV_N + gcol + 32] = f2bf(xh);
        }
      }
    }
  } else {
#pragma unroll
    for (int n = 0; n < 4; ++n) {
      int gcol = tn * 128 + wn * 64 + n * 16 + l15;
#pragma unroll
      for (int m = 0; m < 4; ++m) {
        int row = m0 + wm * 64 + m * 16 + lg * 4;
#pragma unroll
        for (int r = 0; r < 4; ++r)
          Cf[(size_t)(row + r) * HID + gcol] = acc[m][n][r];
      }
    }
  }
}

// ---------- 4) V transpose: V[b*S+s][kv*64+d] -> Vt[((b*8+kv)*64+d)*2048 + s] ----------
__global__ void k_vtrans(const unsigned short* __restrict__ qkv, unsigned short* __restrict__ vt) {
  __shared__ unsigned short t[64][80];
  int ts = blockIdx.x & 63, td = blockIdx.x >> 6;
  int tid = threadIdx.x;
#pragma unroll
  for (int L = 0; L < 2; ++L) {
    int c = L * 256 + tid;
    int row = c >> 3, ch = c & 7;
    const unsigned short* src = qkv + (size_t)(ts * 64 + row) * QKV_N + 2560 + td * 64 + ch * 8;
    s16x8 v = *(const s16x8*)src;
    int cs = (ch * 8) ^ ((row >> 3) << 3);
    *(s16x8*)&t[row][cs] = v;
  }
  __syncthreads();
  int b = (ts * 64) >> 11;
  int s0 = (ts * 64) & (S_LEN - 1);
#pragma unroll
  for (int L = 0; L < 2; ++L) {
    int c = L * 256 + tid;
    int d = c >> 3, sc = c & 7;
    s16x8 o;
#pragma unroll
    for (int j = 0; j < 8; ++j) o[j] = (short)t[sc * 8 + j][d ^ (sc << 3)];
    unsigned short* dst = vt + ((size_t)((b * 8 + td) * 64 + d)) * 2048 + s0 + sc * 8;
    *(s16x8*)dst = o;
  }
}

// ---------- 5) GQA causal flash attention ----------
// block = one 32-row q-tile of one KV group: 8 waves = 4 heads x 2 row-halves.
// No max-tracking (scores bounded; softmax shift-invariant); Q pre-scaled to log2 domain.
__global__ __launch_bounds__(512, 4) void k_attn(const unsigned short* __restrict__ qkv,
                                                 const unsigned short* __restrict__ vt,
                                                 unsigned short* __restrict__ aout) {
  __shared__ unsigned short lK[2][4096];
  __shared__ unsigned short lV[2][4096];
  __shared__ unsigned short pl[8][1024];   // per-wave P tile [16][64], XOR-swizzled
  int wave = threadIdx.x >> 6, lane = threadIdx.x & 63;
  int l15 = lane & 15, lg = lane >> 4;
  int bi = blockIdx.x;            // 0..1023
  int t  = 63 - (bi >> 4);        // longest-first
  int b  = (bi >> 3) & 1;
  int hg = bi & 7;
  int wh = wave >> 1;             // head within KV group (0..3)
  int mh = wave & 1;              // 16-row half
  int h  = hg * 4 + wh;
  int q0 = t * 32 + mh * 16;
  int kbmax = t >> 1;             // block-uniform

  const unsigned short* qb_ = qkv + (size_t)(b * S_LEN) * QKV_N + h * 64;
  const unsigned short* kbase = qkv + (size_t)(b * S_LEN) * QKV_N + 2048 + hg * 64;
  const unsigned short* vbase = vt + (size_t)((b * NKVH + hg) * 64) * 2048;
  unsigned short* pw = &pl[wave][0];
  int sw = (l15 & 7) << 3;        // element-XOR swizzle for this lane's rows

  int srow = wave * 8 + (lane >> 3);
  int ssw = 8 * ((lane & 7) ^ ((lane >> 3) & 7));
  const unsigned short* gk0 = kbase + (size_t)srow * QKV_N + ssw;
  const unsigned short* gv0 = vbase + (size_t)srow * 2048 + ssw;
  short* lkd0 = (short*)&lK[0][wave * 512]; short* lkd1 = (short*)&lK[1][wave * 512];
  short* lvd0 = (short*)&lV[0][wave * 512]; short* lvd1 = (short*)&lV[1][wave * 512];

  // Q fragments (B-operand of swapped QK^T); already scaled by 0.125*log2e
  s16x8 aq[2];
#pragma unroll
  for (int ks = 0; ks < 2; ++ks)
    aq[ks] = *(const s16x8*)(qb_ + (size_t)(q0 + l15) * QKV_N + ks * 32 + lg * 8);

  f32x4 acc[4];
#pragma unroll
  for (int dt = 0; dt < 4; ++dt) acc[dt] = (f32x4){0.f, 0.f, 0.f, 0.f};
  float lrow = 0.f;

  gl_lds16(gk0, lkd0);
  gl_lds16(gv0, lvd0);
  asm volatile("s_waitcnt vmcnt(0)" ::: "memory");
  __syncthreads();

  for (int kb = 0; kb <= kbmax; ++kb) {
    const unsigned short* lk = &lK[kb & 1][0];
    const unsigned short* lv = &lV[kb & 1][0];
    if (kb < kbmax) {
      size_t go = (size_t)(kb + 1) * 64;
      if ((kb & 1) == 0) { gl_lds16(gk0 + go * QKV_N, lkd1); gl_lds16(gv0 + go, lvd1); }
      else               { gl_lds16(gk0 + go * QKV_N, lkd0); gl_lds16(gv0 + go, lvd0); }
    }
    bool need_mask = (kb == kbmax);
    // QK^T (swapped): lane column = q (l15), rows = k
    f32x4 z[4];
    __builtin_amdgcn_s_setprio(1);
#pragma unroll
    for (int nt = 0; nt < 4; ++nt) {
      s16x8 k0 = *(const s16x8*)(lk + (nt * 16 + l15) * 64 + ((lg * 8) ^ sw));
      s16x8 k1 = *(const s16x8*)(lk + (nt * 16 + l15) * 64 + ((32 + lg * 8) ^ sw));
      f32x4 zz = (f32x4){0.f, 0.f, 0.f, 0.f};
      zz = __builtin_amdgcn_mfma_f32_16x16x32_bf16(k0, aq[0], zz, 0, 0, 0);
      zz = __builtin_amdgcn_mfma_f32_16x16x32_bf16(k1, aq[1], zz, 0, 0, 0);
      z[nt] = zz;
    }
    __builtin_amdgcn_s_setprio(0);
    // softmax without max-tracking: P = exp2(s)
    int q = q0 + l15;
    float rs = 0.f;
#pragma unroll
    for (int nt = 0; nt < 4; ++nt) {
      float p[4];
#pragma unroll
      for (int r = 0; r < 4; ++r) {
        float v = z[nt][r];
        if (need_mask) {
          int k = kb * 64 + nt * 16 + lg * 4 + r;
          if (k > q) v = -1.0e30f;
        }
        p[r] = __builtin_amdgcn_exp2f(v);
      }
      rs += (p[0] + p[1]) + (p[2] + p[3]);
      u32x2 w;
      w[0] = cvt_pk_bf16(p[0], p[1]);
      w[1] = cvt_pk_bf16(p[2], p[3]);
      *(u32x2*)(pw + l15 * 64 + ((nt * 16 + lg * 4) ^ sw)) = w;
    }
    rs += __shfl_xor(rs, 16);
    rs += __shfl_xor(rs, 32);
    lrow += rs;
    // P fragments (DS ops wave-ordered: reads see this wave's writes)
    s16x8 pa0 = *(const s16x8*)(pw + l15 * 64 + ((lg * 8) ^ sw));
    s16x8 pa1 = *(const s16x8*)(pw + l15 * 64 + ((32 + lg * 8) ^ sw));
    // PV
    __builtin_amdgcn_s_setprio(1);
#pragma unroll
    for (int dt = 0; dt < 4; ++dt) {
      s16x8 v0 = *(const s16x8*)(lv + (dt * 16 + l15) * 64 + ((lg * 8) ^ sw));
      s16x8 v1 = *(const s16x8*)(lv + (dt * 16 + l15) * 64 + ((32 + lg * 8) ^ sw));
      acc[dt] = __builtin_amdgcn_mfma_f32_16x16x32_bf16(pa0, v0, acc[dt], 0, 0, 0);
      acc[dt] = __builtin_amdgcn_mfma_f32_16x16x32_bf16(pa1, v1, acc[dt], 0, 0, 0);
    }
    __builtin_amdgcn_s_setprio(0);
    asm volatile("s_waitcnt vmcnt(0)" ::: "memory");
    __syncthreads();
  }

  // epilogue: O = acc / l
  unsigned short* ob = aout + (size_t)(b * S_LEN) * HID + h * 64;
#pragma unroll
  for (int r = 0; r < 4; ++r) {
    float lr = __shfl(lrow, lg * 4 + r);
    float inv = 1.0f / lr;
#pragma unroll
    for (int dt = 0; dt < 4; ++dt)
      ob[(size_t)(q0 + lg * 4 + r) * HID + dt * 16 + l15] = f2bf(acc[dt][r] * inv);
  }
}

// ---------- launch ----------
extern "C" void kernel_launch(void* const* d_in, const int* in_sizes, int n_in,
                              void* d_out, int out_size, void* d_ws, size_t ws_size,
                              hipStream_t stream) {
  const float* x  = (const float*)d_in[0];
  const float* qw = (const float*)d_in[1];
  const float* qb = (const float*)d_in[2];
  const float* kw = (const float*)d_in[3];
  const float* kbias = (const float*)d_in[4];
  const float* vw = (const float*)d_in[5];
  const float* vbias = (const float*)d_in[6];
  const float* ow = (const float*)d_in[7];

  unsigned short* Xb  = (unsigned short*)d_ws;          // 8388608
  unsigned short* Wqb = Xb + 8388608;                   // 4194304
  unsigned short* Wkb = Wqb + 4194304;                  // 1048576
  unsigned short* Wvb = Wkb + 1048576;                  // 1048576
  unsigned short* Wob = Wvb + 1048576;                  // 4194304
  unsigned short* QKV = Wob + 4194304;                  // 4096*3072
  unsigned short* VT  = QKV + 12582912;                 // 2*8*64*2048
  unsigned short* AO  = VT + 2097152;                   // 4096*2048
  float* COS = (float*)(AO + 8388608);                  // 65536 f32
  float* SIN = COS + 65536;

  k_convert<<<1024, 256, 0, stream>>>(x, qw, kw, vw, ow, Xb);
  k_rope_table<<<256, 256, 0, stream>>>(COS, SIN);
  k_gemm<0><<<dim3(24, 32), 256, 0, stream>>>(Xb, Wqb, Wkb, Wvb, qb, kbias, vbias,
                                              COS, SIN, QKV, nullptr);
  k_vtrans<<<512, 256, 0, stream>>>(QKV, VT);
  k_attn<<<1024, 512, 0, stream>>>(QKV, VT, AO);
  k_gemm<1><<<dim3(16, 32), 256, 0, stream>>>(AO, Wob, nullptr, nullptr,
                                              nullptr, nullptr, nullptr, nullptr, nullptr,
                                              nullptr, (float*)d_out);
}